// Round 1
// 190.485 us; speedup vs baseline: 1.1453x; 1.1453x over previous
//
#include <hip/hip_runtime.h>

// MFMA fragment types (gfx950): 16x16x32 f16 -> A/B = 8 x _Float16, C/D = 4 x float
typedef _Float16 half8 __attribute__((ext_vector_type(8)));
typedef __fp16 fp16x2 __attribute__((ext_vector_type(2)));   // cvt_pkrtz return type
typedef float floatx4 __attribute__((ext_vector_type(4)));

#define MSGW 64      // message width
#define DEG 8        // fixed in-degree; triplets per edge

// softplus(x) = max(x,0) + ln(1 + exp(-|x|)), via native v_exp_f32/v_log_f32 (log2-based)
__device__ __forceinline__ float softplus_f(float x) {
    float ax = __builtin_fabsf(x);
    float t  = __builtin_amdgcn_exp2f(-1.44269504089f * ax);   // exp(-|x|)
    float l  = 0.69314718056f * __builtin_amdgcn_logf(1.0f + t);
    return fmaxf(x, 0.0f) + l;
}

__device__ __forceinline__ half8 cvt8(const float* p) {
    float4 x = *(const float4*)p;
    float4 y = *(const float4*)(p + 4);
    fp16x2 p0 = __builtin_amdgcn_cvt_pkrtz(x.x, x.y);
    fp16x2 p1 = __builtin_amdgcn_cvt_pkrtz(x.z, x.w);
    fp16x2 p2 = __builtin_amdgcn_cvt_pkrtz(y.x, y.y);
    fp16x2 p3 = __builtin_amdgcn_cvt_pkrtz(y.z, y.w);
    half8 h;
    h[0] = (_Float16)p0[0]; h[1] = (_Float16)p0[1];
    h[2] = (_Float16)p1[0]; h[3] = (_Float16)p1[1];
    h[4] = (_Float16)p2[0]; h[5] = (_Float16)p2[1];
    h[6] = (_Float16)p3[0]; h[7] = (_Float16)p3[1];
    return h;
}

// softplus over a half8 (fp16 in, fp16 out via cvt_pkrtz pairs)
__device__ __forceinline__ half8 sp8(half8 z) {
    half8 h;
#pragma unroll
    for (int j = 0; j < 8; j += 2) {
        fp16x2 pk = __builtin_amdgcn_cvt_pkrtz(softplus_f((float)z[j]),
                                               softplus_f((float)z[j + 1]));
        h[j] = (_Float16)pk[0]; h[j + 1] = (_Float16)pk[1];
    }
    return h;
}

// ---------------------------------------------------------------------------
// Kernel 1: per-edge layer-1 projection.
//   PQ[e][0:64]   = messages[e] @ W1[0:64, :]            (P, consumed via kj)
//   PQ[e][64:128] = messages[e] @ W1[64:128, :] + b1     (Q, consumed via ji)
// Stored fp16, [E x 128]. One wave = 16 edge rows, 16 MFMAs (K=64, N=128).
// ---------------------------------------------------------------------------
__global__ __launch_bounds__(256, 2)
void edge_proj_kernel(const float* __restrict__ messages,
                      const float* __restrict__ W1, const float* __restrict__ b1,
                      _Float16* __restrict__ PQ, int E)
{
    __shared__ _Float16 lw1x[16 * 512];       // 16 B-fragments (nt*2+ks), lane-order
    __shared__ _Float16 lrep[4][16 * 132];    // per-wave C->row repack, stride 132 (no conflicts)

    const int tid = threadIdx.x;
    // stage W1 as fragment-lane-order fp16: frag f=(nt*2+ks), value W1x[k][n']
    for (int i = tid; i < 64 * 128; i += 256) {
        int k = i >> 7, np = i & 127;
        float v = (np < 64) ? W1[k * 64 + np] : W1[(64 + k) * 64 + (np - 64)];
        int ks = k >> 5, qq = (k >> 3) & 3, j = k & 7;
        int nt = np >> 4, sdx = np & 15;
        lw1x[(nt * 2 + ks) * 512 + (qq * 16 + sdx) * 8 + j] = (_Float16)v;
    }
    __syncthreads();

    const int wave = tid >> 6;
    const int lane = tid & 63;
    const int s = lane & 15;
    const int q = lane >> 4;
    const int wtile = blockIdx.x * 4 + wave;
    const int e0 = wtile * 16;
    if (e0 >= E) return;

    float b1v[4];
#pragma unroll
    for (int nt = 0; nt < 4; ++nt) b1v[nt] = b1[nt * 16 + s];

    int er = e0 + s; if (er >= E) er = E - 1;
    const float* mp = messages + (size_t)er * MSGW + q * 8;
    half8 af0 = cvt8(mp);
    half8 af1 = cvt8(mp + 32);

    floatx4 acc[8];
#pragma unroll
    for (int nt = 0; nt < 4; ++nt) { floatx4 z = {0.f, 0.f, 0.f, 0.f}; acc[nt] = z; }
#pragma unroll
    for (int nt = 4; nt < 8; ++nt) {
        float bv = b1v[nt - 4];
        floatx4 iv = {bv, bv, bv, bv};
        acc[nt] = iv;
    }
#pragma unroll
    for (int nt = 0; nt < 8; ++nt) {
        half8 bf0 = *(const half8*)&lw1x[(nt * 2 + 0) * 512 + lane * 8];
        acc[nt] = __builtin_amdgcn_mfma_f32_16x16x32_f16(af0, bf0, acc[nt], 0, 0, 0);
        half8 bf1 = *(const half8*)&lw1x[(nt * 2 + 1) * 512 + lane * 8];
        acc[nt] = __builtin_amdgcn_mfma_f32_16x16x32_f16(af1, bf1, acc[nt], 0, 0, 0);
    }

    // C-layout -> row-major fp16 via wave-private LDS, then coalesced 16B stores.
    // write bank check: addr = (q*4+rr)*264B + nt*32B + s*2B -> q gives +{0,8,16,24} banks,
    // s spans 8 banks 2-way: conflict-free.
    _Float16* rep = lrep[wave];
#pragma unroll
    for (int nt = 0; nt < 8; ++nt)
#pragma unroll
        for (int rr = 0; rr < 4; ++rr)
            rep[(q * 4 + rr) * 132 + nt * 16 + s] = (_Float16)acc[nt][rr];
    __asm__ volatile("s_waitcnt lgkmcnt(0)" ::: "memory");

#pragma unroll
    for (int cc = 0; cc < 4; ++cc) {
        int c = cc * 64 + lane;
        int rrow = c >> 4, c16 = c & 15;
        half8 v = *(const half8*)&rep[rrow * 132 + c16 * 8];
        int eg = e0 + rrow;
        if (eg < E)
            *(half8*)&PQ[(size_t)eg * 128 + c16 * 8] = v;
    }
}

// ---------------------------------------------------------------------------
// Kernel 2: main triplet kernel. Layer 1 is now a gather+fp16-add of PQ rows,
// produced directly in MFMA A-fragment layout (no cvt8, no LDS repack, no
// layer-1 MFMA). W2 fragments hoisted into 32 VGPRs; only LDS traffic in the
// loop is the shuffle network. Structural facts: idx_ji[t]=t>>3, idx_j=kj>>3.
// ---------------------------------------------------------------------------
__global__ __launch_bounds__(256, 3)
void triplet_mlp2_kernel(const _Float16* __restrict__ PQ,
                         const float* __restrict__ r2,
                         const float* __restrict__ W2, const float* __restrict__ b2,
                         const float* __restrict__ W3, const float* __restrict__ b3,
                         const int* __restrict__ idx_kj,
                         float* __restrict__ sacc, float* __restrict__ cnt,
                         int nChunks)
{
    __shared__ _Float16 lw2x[8 * 512];   // 8 fragments (nt*2+ks), lane-order (8 KB)

    const int tid = threadIdx.x;
    for (int i = tid; i < 64 * 64; i += 256) {
        int k = i >> 6, n = i & 63;
        int ks = k >> 5, qq = (k >> 3) & 3, j = k & 7;
        int nt = n >> 4, sdx = n & 15;
        lw2x[(nt * 2 + ks) * 512 + (qq * 16 + sdx) * 8 + j] = (_Float16)W2[i];
    }
    __syncthreads();

    const int wave = tid >> 6;
    const int lane = tid & 63;
    const int s = lane & 15;
    const int q = lane >> 4;

    // hoist weights: W2 fragments (32 VGPR), b2/W3 per-lane scalars, b3 uniform
    half8 w2f[2][4];
#pragma unroll
    for (int nt = 0; nt < 4; ++nt) {
        w2f[0][nt] = *(const half8*)&lw2x[(nt * 2 + 0) * 512 + lane * 8];
        w2f[1][nt] = *(const half8*)&lw2x[(nt * 2 + 1) * 512 + lane * 8];
    }
    float b2v[4], w3v[4];
#pragma unroll
    for (int nt = 0; nt < 4; ++nt) {
        b2v[nt] = b2[nt * 16 + s];
        w3v[nt] = W3[nt * 16 + s];
    }
    const float b3v = b3[0];

    const int T = nChunks * 64;
    const int stride = gridDim.x * 64;

    int t = blockIdx.x * 64 + wave * 16 + s;
    int kj = (t < T) ? idx_kj[t] : 0;

    for (int chunk = blockIdx.x; chunk < nChunks; chunk += gridDim.x) {
        const int t_next = t + stride;
        const int kj_next = idx_kj[(t_next < T) ? t_next : 0];

        const int ji = t >> 3;                   // idx_ji[t] structural
        const int jn = kj >> 3;                  // idx_j[t] structural

        // layer 1 = gather + fp16 add, directly in A-fragment layout:
        // lane (s,q) needs h1[row s][q*8+j] (ks=0) and h1[row s][32+q*8+j] (ks=1)
        const _Float16* pk_ = PQ + (size_t)kj * 128 + q * 8;        // P part
        const _Float16* pj_ = PQ + (size_t)ji * 128 + 64 + q * 8;   // Q part (b1 folded)
        half8 z0 = *(const half8*)pk_        + *(const half8*)pj_;
        half8 z1 = *(const half8*)(pk_ + 32) + *(const half8*)(pj_ + 32);
        half8 a20 = sp8(z0);
        half8 a21 = sp8(z1);

        const float rk0 = r2[(size_t)kj * 2];
        const float rk1 = r2[(size_t)kj * 2 + 1];

        // ---- layer 2: [16 x 64] @ [64 x 64], B from registers ----
        floatx4 acc2[4];
#pragma unroll
        for (int nt = 0; nt < 4; ++nt) {
            float bv = b2v[nt];
            floatx4 iv = {bv, bv, bv, bv};
            acc2[nt] = iv;
        }
#pragma unroll
        for (int nt = 0; nt < 4; ++nt) {
            acc2[nt] = __builtin_amdgcn_mfma_f32_16x16x32_f16(a20, w2f[0][nt], acc2[nt], 0, 0, 0);
            acc2[nt] = __builtin_amdgcn_mfma_f32_16x16x32_f16(a21, w2f[1][nt], acc2[nt], 0, 0, 0);
        }

        // ---- layer 3: m = softplus(h2) . W3  (64 hidden = 4 regs x 16 lanes) ----
        float part[4];
#pragma unroll
        for (int rr = 0; rr < 4; ++rr) {
            float p = 0.0f;
#pragma unroll
            for (int nt = 0; nt < 4; ++nt)
                p += softplus_f(acc2[nt][rr]) * w3v[nt];
            part[rr] = p;
        }
#pragma unroll
        for (int mask = 1; mask < 16; mask <<= 1)
#pragma unroll
            for (int rr = 0; rr < 4; ++rr)
                part[rr] += __shfl_xor(part[rr], mask, 16);

        // distribute: lane (s,q) fetches m for row s (held by quad s>>2, reg s&3)
        const int srcl = (s >> 2) << 4;
        float mr[4];
#pragma unroll
        for (int rr = 0; rr < 4; ++rr)
            mr[rr] = __shfl(part[rr], srcl, 64);
        const int rsel = s & 3;
        float m_mine = mr[0];
        m_mine = (rsel == 1) ? mr[1] : m_mine;
        m_mine = (rsel == 2) ? mr[2] : m_mine;
        m_mine = (rsel == 3) ? mr[3] : m_mine;
        m_mine += b3v;

        // per-edge pooled vector v[b] = sum_k m_k * rk_k[b]; quads split the b component
        float c = m_mine * ((q & 1) ? rk1 : rk0);
        c += __shfl_xor(c, 1, 16);
        c += __shfl_xor(c, 2, 16);
        c += __shfl_xor(c, 4, 16);   // lane s=0: edge A sum, s=8: edge B sum (for b = q&1)

        if ((s & 7) == 0) {
            const int aa = q >> 1, bb = q & 1;          // dyad component: rj[aa]*v[bb]
            const float rj = r2[(size_t)ji * 2 + aa];   // this lane's own ji == its edge
            atomicAdd(&sacc[(size_t)jn * 4 + aa * 2 + bb], rj * c);
            if (q == 0) atomicAdd(&cnt[jn], 8.0f);      // 8 triplets pooled per edge
        }

        t = t_next;
        kj = kj_next;
    }
}

// ---------------------------------------------------------------------------
// Fallback: previous verified single-pass kernel (used if ws_size can't hold PQ)
// ---------------------------------------------------------------------------
__global__ __launch_bounds__(256, 3)
void triplet_mlp_fb_kernel(const float* __restrict__ messages,
                           const float* __restrict__ r2,
                           const float* __restrict__ W1, const float* __restrict__ b1,
                           const float* __restrict__ W2, const float* __restrict__ b2,
                           const float* __restrict__ W3, const float* __restrict__ b3,
                           const int* __restrict__ idx_kj,
                           float* __restrict__ sacc, float* __restrict__ cnt,
                           int nChunks)
{
    __shared__ _Float16 lw1x[16 * 512];
    __shared__ _Float16 lw2x[8 * 512];
    __shared__ float lb1[64], lb2[64], lw3[64];
    __shared__ _Float16 lh[4][16 * 72];

    const int tid = threadIdx.x;
    for (int i = tid; i < 128 * 64; i += 256) {
        int k = i >> 6, n = i & 63;
        int ks = k >> 5, q = (k >> 3) & 3, j = k & 7;
        int nt = n >> 4, s = n & 15;
        lw1x[(nt * 4 + ks) * 512 + (q * 16 + s) * 8 + j] = (_Float16)W1[i];
    }
    for (int i = tid; i < 64 * 64; i += 256) {
        int k = i >> 6, n = i & 63;
        int ks = k >> 5, q = (k >> 3) & 3, j = k & 7;
        int nt = n >> 4, s = n & 15;
        lw2x[(nt * 2 + ks) * 512 + (q * 16 + s) * 8 + j] = (_Float16)W2[i];
    }
    if (tid < 64) { lb1[tid] = b1[tid]; lb2[tid] = b2[tid]; lw3[tid] = W3[tid]; }
    __syncthreads();

    const int wave = tid >> 6;
    const int lane = tid & 63;
    const int s = lane & 15;
    const int q = lane >> 4;
    const float b3v = b3[0];
    const int T = nChunks * 64;
    const int stride = gridDim.x * 64;

    _Float16* myh = lh[wave];

    int t = blockIdx.x * 64 + wave * 16 + s;
    int kj = (t < T) ? idx_kj[t] : 0;

    for (int chunk = blockIdx.x; chunk < nChunks; chunk += gridDim.x) {
        const int t_next = t + stride;
        const int kj_next = idx_kj[(t_next < T) ? t_next : 0];

        const int ji = t >> 3;
        const int jn = kj >> 3;

        const float* mk = messages + (size_t)kj * MSGW + q * 8;
        const float* mj = messages + (size_t)ji * MSGW + q * 8;
        half8 afr[4];
        afr[0] = cvt8(mk);
        afr[1] = cvt8(mk + 32);
        afr[2] = cvt8(mj);
        afr[3] = cvt8(mj + 32);

        const float rk0 = r2[(size_t)kj * 2];
        const float rk1 = r2[(size_t)kj * 2 + 1];

        floatx4 acc[4];
#pragma unroll
        for (int nt = 0; nt < 4; ++nt) {
            float bv = lb1[nt * 16 + s];
            floatx4 iv = {bv, bv, bv, bv};
            acc[nt] = iv;
        }
#pragma unroll
        for (int ks = 0; ks < 4; ++ks)
#pragma unroll
            for (int nt = 0; nt < 4; ++nt) {
                half8 bf = *(const half8*)&lw1x[(nt * 4 + ks) * 512 + lane * 8];
                acc[nt] = __builtin_amdgcn_mfma_f32_16x16x32_f16(afr[ks], bf, acc[nt], 0, 0, 0);
            }

#pragma unroll
        for (int nt = 0; nt < 4; ++nt)
#pragma unroll
            for (int rr = 0; rr < 4; ++rr)
                myh[(q * 4 + rr) * 72 + nt * 16 + s] = (_Float16)softplus_f(acc[nt][rr]);
        __asm__ volatile("s_waitcnt lgkmcnt(0)" ::: "memory");

        half8 a2[2];
        a2[0] = *(const half8*)&myh[s * 72 + q * 8];
        a2[1] = *(const half8*)&myh[s * 72 + 32 + q * 8];
        __asm__ volatile("" ::: "memory");

        floatx4 acc2[4];
#pragma unroll
        for (int nt = 0; nt < 4; ++nt) {
            float bv = lb2[nt * 16 + s];
            floatx4 iv = {bv, bv, bv, bv};
            acc2[nt] = iv;
        }
#pragma unroll
        for (int ks = 0; ks < 2; ++ks)
#pragma unroll
            for (int nt = 0; nt < 4; ++nt) {
                half8 bf = *(const half8*)&lw2x[(nt * 2 + ks) * 512 + lane * 8];
                acc2[nt] = __builtin_amdgcn_mfma_f32_16x16x32_f16(a2[ks], bf, acc2[nt], 0, 0, 0);
            }

        float part[4];
#pragma unroll
        for (int rr = 0; rr < 4; ++rr) {
            float p = 0.0f;
#pragma unroll
            for (int nt = 0; nt < 4; ++nt)
                p += softplus_f(acc2[nt][rr]) * lw3[nt * 16 + s];
            part[rr] = p;
        }
#pragma unroll
        for (int mask = 1; mask < 16; mask <<= 1)
#pragma unroll
            for (int rr = 0; rr < 4; ++rr)
                part[rr] += __shfl_xor(part[rr], mask, 16);

        const int srcl = (s >> 2) << 4;
        float mr[4];
#pragma unroll
        for (int rr = 0; rr < 4; ++rr)
            mr[rr] = __shfl(part[rr], srcl, 64);
        const int rsel = s & 3;
        float m_mine = mr[0];
        m_mine = (rsel == 1) ? mr[1] : m_mine;
        m_mine = (rsel == 2) ? mr[2] : m_mine;
        m_mine = (rsel == 3) ? mr[3] : m_mine;
        m_mine += b3v;

        float c = m_mine * ((q & 1) ? rk1 : rk0);
        c += __shfl_xor(c, 1, 16);
        c += __shfl_xor(c, 2, 16);
        c += __shfl_xor(c, 4, 16);

        if ((s & 7) == 0) {
            const int aa = q >> 1, bb = q & 1;
            const float rj = r2[(size_t)ji * 2 + aa];
            atomicAdd(&sacc[(size_t)jn * 4 + aa * 2 + bb], rj * c);
            if (q == 0) atomicAdd(&cnt[jn], 8.0f);
        }

        t = t_next;
        kj = kj_next;
    }
}

__global__ void finalize_kernel(const float* __restrict__ sacc, const float* __restrict__ cnt,
                                float* __restrict__ out, int n4) {
    int i = blockIdx.x * 256 + threadIdx.x;
    if (i < n4) {
        float c = cnt[i >> 2];
        out[i] = sacc[i] / fmaxf(c, 1.0f);
    }
}

extern "C" void kernel_launch(void* const* d_in, const int* in_sizes, int n_in,
                              void* d_out, int out_size, void* d_ws, size_t ws_size,
                              hipStream_t stream) {
    const float* messages = (const float*)d_in[0];
    const float* r2       = (const float*)d_in[1];
    const float* W1       = (const float*)d_in[2];
    const float* b1       = (const float*)d_in[3];
    const float* W2       = (const float*)d_in[4];
    const float* b2       = (const float*)d_in[5];
    const float* W3       = (const float*)d_in[6];
    const float* b3       = (const float*)d_in[7];
    const int* idx_kj     = (const int*)d_in[8];

    const int T = in_sizes[8];          // 1,280,000 triplets
    const int E = T / DEG;              // 160,000 edges
    const int N = out_size / 4;         // 20,000 nodes
    float* sacc = (float*)d_ws;         // [N*4] pooled sums
    float* cntp = sacc + (size_t)N * 4; // [N] counts

    (void)hipMemsetAsync(d_ws, 0, (size_t)N * 5 * sizeof(float), stream);

    const int nChunks = T / 64;
    int grid = nChunks < 4096 ? nChunks : 4096;

    const size_t pqOff  = (((size_t)N * 5 * sizeof(float)) + 255) & ~(size_t)255;
    const size_t needWs = pqOff + (size_t)E * 128 * sizeof(_Float16);

    if (ws_size >= needWs) {
        _Float16* PQ = (_Float16*)((char*)d_ws + pqOff);
        const int tiles = (E + 15) / 16;
        const int pblocks = (tiles + 3) / 4;
        edge_proj_kernel<<<pblocks, 256, 0, stream>>>(messages, W1, b1, PQ, E);
        triplet_mlp2_kernel<<<grid, 256, 0, stream>>>(PQ, r2, W2, b2, W3, b3,
                                                      idx_kj, sacc, cntp, nChunks);
    } else {
        triplet_mlp_fb_kernel<<<grid, 256, 0, stream>>>(messages, r2, W1, b1, W2, b2, W3, b3,
                                                        idx_kj, sacc, cntp, nChunks);
    }

    const int n4 = N * 4;
    finalize_kernel<<<(n4 + 255) / 256, 256, 0, stream>>>(sacc, cntp, (float*)d_out, n4);
}

// Round 2
// 186.821 us; speedup vs baseline: 1.1677x; 1.0196x over previous
//
#include <hip/hip_runtime.h>

// MFMA fragment types (gfx950): 16x16x32 f16 -> A/B = 8 x _Float16, C/D = 4 x float
typedef _Float16 half8 __attribute__((ext_vector_type(8)));
typedef __fp16 fp16x2 __attribute__((ext_vector_type(2)));   // cvt_pkrtz return type
typedef float floatx4 __attribute__((ext_vector_type(4)));

#define MSGW 64      // message width
#define DEG 8        // fixed in-degree; triplets per edge

// softplus(x) = max(x,0) + ln(1 + exp(-|x|)), via native v_exp_f32/v_log_f32 (log2-based)
__device__ __forceinline__ float softplus_f(float x) {
    float ax = __builtin_fabsf(x);
    float t  = __builtin_amdgcn_exp2f(-1.44269504089f * ax);   // exp(-|x|)
    float l  = 0.69314718056f * __builtin_amdgcn_logf(1.0f + t);
    return fmaxf(x, 0.0f) + l;
}

__device__ __forceinline__ half8 cvt8(const float* p) {
    float4 x = *(const float4*)p;
    float4 y = *(const float4*)(p + 4);
    fp16x2 p0 = __builtin_amdgcn_cvt_pkrtz(x.x, x.y);
    fp16x2 p1 = __builtin_amdgcn_cvt_pkrtz(x.z, x.w);
    fp16x2 p2 = __builtin_amdgcn_cvt_pkrtz(y.x, y.y);
    fp16x2 p3 = __builtin_amdgcn_cvt_pkrtz(y.z, y.w);
    half8 h;
    h[0] = (_Float16)p0[0]; h[1] = (_Float16)p0[1];
    h[2] = (_Float16)p1[0]; h[3] = (_Float16)p1[1];
    h[4] = (_Float16)p2[0]; h[5] = (_Float16)p2[1];
    h[6] = (_Float16)p3[0]; h[7] = (_Float16)p3[1];
    return h;
}

// softplus over a half8 (fp16 in, fp16 out via cvt_pkrtz pairs)
__device__ __forceinline__ half8 sp8(half8 z) {
    half8 h;
#pragma unroll
    for (int j = 0; j < 8; j += 2) {
        fp16x2 pk = __builtin_amdgcn_cvt_pkrtz(softplus_f((float)z[j]),
                                               softplus_f((float)z[j + 1]));
        h[j] = (_Float16)pk[0]; h[j + 1] = (_Float16)pk[1];
    }
    return h;
}

// DPP-based cross-lane adds (register-only, no DS pipe).
// quad_perm xor1 = [1,0,3,2] = 0xB1 ; xor2 = [2,3,0,1] = 0x4E
// ROW_HALF_MIRROR = 0x141 (i <-> 7-i within each 8) ; ROW_MIRROR = 0x140 (i <-> 15-i)
template<int CTRL>
__device__ __forceinline__ float dpp_addf(float x) {
    int y = __builtin_amdgcn_update_dpp(0, __float_as_int(x), CTRL, 0xF, 0xF, true);
    return x + __int_as_float(y);
}
// full sum over the 16 lanes of a DPP row (mirror-based: direction-unambiguous)
__device__ __forceinline__ float red16(float x) {
    x = dpp_addf<0xB1>(x);   // + xor1  -> pair sums
    x = dpp_addf<0x4E>(x);   // + xor2  -> quad sums
    x = dpp_addf<0x141>(x);  // + half-mirror -> 8-lane sums
    x = dpp_addf<0x140>(x);  // + mirror      -> 16-lane sum (all lanes)
    return x;
}
// sum over each 8-lane half of a DPP row (lanes 0..7 get sum(0..7), 8..15 get sum(8..15))
__device__ __forceinline__ float red8(float x) {
    x = dpp_addf<0xB1>(x);
    x = dpp_addf<0x4E>(x);
    x = dpp_addf<0x141>(x);
    return x;
}

// ---------------------------------------------------------------------------
// Kernel 0: one-time weight permutation into MFMA B-fragment lane order (fp16).
// W1f: 16 frags f = nt*2+ks (nt 0..7 over 128 outputs [P|Q], ks 0..1 over k 0..63)
// W2f:  8 frags f = nt*2+ks (nt 0..3 over 64 outputs,       ks 0..1)
// frag layout: W*f[f*512 + lane*8 + j] = W[k = ks*32 + (lane>>4)*8 + j][n = nt*16 + (lane&15)]
// ---------------------------------------------------------------------------
__global__ void prep_weights_kernel(const float* __restrict__ W1, const float* __restrict__ W2,
                                    _Float16* __restrict__ W1f, _Float16* __restrict__ W2f) {
    const int tid = threadIdx.x;
    for (int idx = tid; idx < 16 * 512; idx += 256) {
        int f = idx >> 9, lane = (idx >> 3) & 63, j = idx & 7;
        int nt = f >> 1, ks = f & 1;
        int k = ks * 32 + (lane >> 4) * 8 + j;
        int np = nt * 16 + (lane & 15);
        float v = (np < 64) ? W1[k * 64 + np] : W1[(64 + k) * 64 + (np - 64)];
        W1f[idx] = (_Float16)v;
    }
    for (int idx = tid; idx < 8 * 512; idx += 256) {
        int f = idx >> 9, lane = (idx >> 3) & 63, j = idx & 7;
        int nt = f >> 1, ks = f & 1;
        int k = ks * 32 + (lane >> 4) * 8 + j;
        int n = nt * 16 + (lane & 15);
        W2f[idx] = (_Float16)W2[k * 64 + n];
    }
}

// ---------------------------------------------------------------------------
// Kernel 1: per-edge layer-1 projection.
//   PQ[e][0:64]   = messages[e] @ W1[0:64, :]            (P, consumed via kj)
//   PQ[e][64:128] = messages[e] @ W1[64:128, :] + b1     (Q, consumed via ji)
// Stored fp16, [E x 128]. One wave = 16 edge rows, 16 MFMAs. Grid-strided;
// W1 staged once per block by LINEAR half8 copy from pre-permuted W1f.
// ---------------------------------------------------------------------------
__global__ __launch_bounds__(256, 2)
void edge_proj_kernel(const float* __restrict__ messages,
                      const _Float16* __restrict__ W1f, const float* __restrict__ b1,
                      _Float16* __restrict__ PQ, int E, int nbt)
{
    __shared__ __align__(16) _Float16 lw1x[16 * 512];     // 16 B-fragments, lane-order
    __shared__ __align__(16) _Float16 lrep[4][16 * 132];  // per-wave C->row repack

    const int tid = threadIdx.x;
    for (int i = tid; i < 1024; i += 256)                 // 1024 x half8 = 16 KB linear copy
        *(half8*)&lw1x[i * 8] = *(const half8*)&W1f[i * 8];
    __syncthreads();

    const int wave = tid >> 6;
    const int lane = tid & 63;
    const int s = lane & 15;
    const int q = lane >> 4;

    float b1v[4];
#pragma unroll
    for (int nt = 0; nt < 4; ++nt) b1v[nt] = b1[nt * 16 + s];

    _Float16* rep = lrep[wave];

    for (int bt = blockIdx.x; bt < nbt; bt += gridDim.x) {
        const int e0 = (bt * 4 + wave) * 16;
        if (e0 >= E) continue;
        int er = e0 + s; if (er >= E) er = E - 1;
        const float* mp = messages + (size_t)er * MSGW + q * 8;
        half8 af0 = cvt8(mp);
        half8 af1 = cvt8(mp + 32);

        floatx4 acc[8];
#pragma unroll
        for (int nt = 0; nt < 4; ++nt) { floatx4 z = {0.f, 0.f, 0.f, 0.f}; acc[nt] = z; }
#pragma unroll
        for (int nt = 4; nt < 8; ++nt) {
            float bv = b1v[nt - 4];
            floatx4 iv = {bv, bv, bv, bv};
            acc[nt] = iv;
        }
#pragma unroll
        for (int nt = 0; nt < 8; ++nt) {
            half8 bf0 = *(const half8*)&lw1x[(nt * 2 + 0) * 512 + lane * 8];
            acc[nt] = __builtin_amdgcn_mfma_f32_16x16x32_f16(af0, bf0, acc[nt], 0, 0, 0);
            half8 bf1 = *(const half8*)&lw1x[(nt * 2 + 1) * 512 + lane * 8];
            acc[nt] = __builtin_amdgcn_mfma_f32_16x16x32_f16(af1, bf1, acc[nt], 0, 0, 0);
        }

        // C-layout -> row-major fp16 via wave-private LDS, then coalesced 16B stores.
        // (DS ops of one wave complete in order -> next iteration's writes can't pass
        //  this iteration's reads.)
#pragma unroll
        for (int nt = 0; nt < 8; ++nt)
#pragma unroll
            for (int rr = 0; rr < 4; ++rr)
                rep[(q * 4 + rr) * 132 + nt * 16 + s] = (_Float16)acc[nt][rr];
        __asm__ volatile("s_waitcnt lgkmcnt(0)" ::: "memory");

#pragma unroll
        for (int cc = 0; cc < 4; ++cc) {
            int c = cc * 64 + lane;
            int rrow = c >> 4, c16 = c & 15;
            half8 v = *(const half8*)&rep[rrow * 132 + c16 * 8];
            int eg = e0 + rrow;
            if (eg < E)
                *(half8*)&PQ[(size_t)eg * 128 + c16 * 8] = v;
        }
        __asm__ volatile("" ::: "memory");
    }
}

// ---------------------------------------------------------------------------
// Kernel 2: main triplet kernel. Zero LDS, no barriers. W2 fragments loaded
// from pre-permuted global W2f into 32 VGPRs. PQ gather software-pipelined one
// tile ahead (idx two ahead). Layer-3 reduce/distribute/pool all in DPP
// (register crossbar) + a single hoisted-address ds_bpermute.
// Structural facts: idx_ji[t]=t>>3, idx_j[t]=idx_kj[t]>>3.
// ---------------------------------------------------------------------------
__global__ __launch_bounds__(256, 3)
void triplet_mlp2_kernel(const _Float16* __restrict__ PQ,
                         const float* __restrict__ r2,
                         const _Float16* __restrict__ W2f,
                         const float* __restrict__ b2,
                         const float* __restrict__ W3, const float* __restrict__ b3,
                         const int* __restrict__ idx_kj,
                         float* __restrict__ sacc, float* __restrict__ cnt,
                         int nChunks)
{
    const int tid = threadIdx.x;
    const int wave = tid >> 6;
    const int lane = tid & 63;
    const int s = lane & 15;
    const int q = lane >> 4;

    // hoist weights: W2 fragments (32 VGPR), b2/W3 per-lane scalars, b3 uniform
    half8 w2f[2][4];
#pragma unroll
    for (int nt = 0; nt < 4; ++nt) {
        w2f[0][nt] = *(const half8*)&W2f[(nt * 2 + 0) * 512 + lane * 8];
        w2f[1][nt] = *(const half8*)&W2f[(nt * 2 + 1) * 512 + lane * 8];
    }
    float b2v[4], w3v[4];
#pragma unroll
    for (int nt = 0; nt < 4; ++nt) {
        b2v[nt] = b2[nt * 16 + s];
        w3v[nt] = W3[nt * 16 + s];
    }
    const float b3v = b3[0];
    // bpermute source lane for the m-distribute: lane (s,q) pulls from lane (s>>2)*16 + s,
    // which (after the local reg-select) holds msum[(s>>2)*4 + (s&3)] = msum[s].
    const int bperm_addr = (((s >> 2) << 4) + s) << 2;

    const int T = nChunks * 64;
    const int stride = gridDim.x * 64;

    // ---- pipeline prologue ----
    int t = blockIdx.x * 64 + wave * 16 + s;        // < T (grid <= nChunks)
    int kj = idx_kj[t];
    int t1 = t + stride; int t1c = (t1 < T) ? t1 : 0;
    int kjn = idx_kj[t1c];

    const _Float16* pk0 = PQ + (size_t)kj * 128 + q * 8;
    const _Float16* pj0 = PQ + (size_t)(t >> 3) * 128 + 64 + q * 8;
    half8 p0 = *(const half8*)pk0;
    half8 p1 = *(const half8*)(pk0 + 32);
    half8 q0 = *(const half8*)pj0;
    half8 q1 = *(const half8*)(pj0 + 32);
    float2 rkv = *(const float2*)(r2 + (size_t)kj * 2);

    for (int chunk = blockIdx.x; chunk < nChunks; chunk += gridDim.x) {
        // idx two tiles ahead; PQ/rk one tile ahead (addresses ready: kjn from last iter)
        int t2 = t + 2 * stride; int t2c = (t2 < T) ? t2 : 0;
        const int kj2 = idx_kj[t2c];
        const _Float16* pkn = PQ + (size_t)kjn * 128 + q * 8;
        const _Float16* pjn = PQ + (size_t)(t1c >> 3) * 128 + 64 + q * 8;
        half8 np0 = *(const half8*)pkn;
        half8 np1 = *(const half8*)(pkn + 32);
        half8 nq0 = *(const half8*)pjn;
        half8 nq1 = *(const half8*)(pjn + 32);
        float2 nrk = *(const float2*)(r2 + (size_t)kjn * 2);

        const int ji = t >> 3;                   // idx_ji[t] structural
        const int jn = kj >> 3;                  // idx_j[t] structural

        // layer 1 = fp16 add of prefetched PQ fragments + softplus (A-frag layout)
        half8 z0 = p0 + q0;
        half8 z1 = p1 + q1;
        half8 a20 = sp8(z0);
        half8 a21 = sp8(z1);

        // ---- layer 2: [16 x 64] @ [64 x 64], B from registers ----
        floatx4 acc2[4];
#pragma unroll
        for (int nt = 0; nt < 4; ++nt) {
            float bv = b2v[nt];
            floatx4 iv = {bv, bv, bv, bv};
            acc2[nt] = iv;
        }
#pragma unroll
        for (int nt = 0; nt < 4; ++nt) {
            acc2[nt] = __builtin_amdgcn_mfma_f32_16x16x32_f16(a20, w2f[0][nt], acc2[nt], 0, 0, 0);
            acc2[nt] = __builtin_amdgcn_mfma_f32_16x16x32_f16(a21, w2f[1][nt], acc2[nt], 0, 0, 0);
        }

        // ---- layer 3: m = softplus(h2) . W3 ; reduce over 64 cols = 4 regs x 16 lanes ----
        float part[4];
#pragma unroll
        for (int rr = 0; rr < 4; ++rr) {
            float p = 0.0f;
#pragma unroll
            for (int nt = 0; nt < 4; ++nt)
                p += softplus_f(acc2[nt][rr]) * w3v[nt];
            part[rr] = red16(p);                 // all 16 row-lanes: msum[q*4+rr]
        }

        // distribute m to row-owner lanes: local reg-select then one bpermute
        const int rsel = s & 3;
        float mm = part[0];
        mm = (rsel == 1) ? part[1] : mm;
        mm = (rsel == 2) ? part[2] : mm;
        mm = (rsel == 3) ? part[3] : mm;         // lane (s,q) holds msum[q*4 + (s&3)]
        mm = __int_as_float(__builtin_amdgcn_ds_bpermute(bperm_addr, __float_as_int(mm)));
        mm += b3v;                               // lane (s,q) holds m for row s

        // per-edge pooled vector v[b] = sum_k m_k * rk_k[b]; quads carry b = q&1
        float c = mm * ((q & 1) ? rkv.y : rkv.x);
        c = red8(c);                             // lanes 0..7: edge A sum, 8..15: edge B

        if ((s & 7) == 0) {
            const int aa = q >> 1, bb = q & 1;          // dyad component: rj[aa]*v[bb]
            const float rj = r2[(size_t)ji * 2 + aa];   // this lane's own ji == its edge
            atomicAdd(&sacc[(size_t)jn * 4 + aa * 2 + bb], rj * c);
            if (q == 0) atomicAdd(&cnt[jn], 8.0f);      // 8 triplets pooled per edge
        }

        // ---- rotate pipeline state ----
        t += stride;
        kj = kjn; kjn = kj2;
        t1c = t2c;
        p0 = np0; p1 = np1; q0 = nq0; q1 = nq1;
        rkv = nrk;
    }
}

// ---------------------------------------------------------------------------
// Fallback: previous verified single-pass kernel (used if ws_size can't hold PQ)
// ---------------------------------------------------------------------------
__global__ __launch_bounds__(256, 3)
void triplet_mlp_fb_kernel(const float* __restrict__ messages,
                           const float* __restrict__ r2,
                           const float* __restrict__ W1, const float* __restrict__ b1,
                           const float* __restrict__ W2, const float* __restrict__ b2,
                           const float* __restrict__ W3, const float* __restrict__ b3,
                           const int* __restrict__ idx_kj,
                           float* __restrict__ sacc, float* __restrict__ cnt,
                           int nChunks)
{
    __shared__ _Float16 lw1x[16 * 512];
    __shared__ _Float16 lw2x[8 * 512];
    __shared__ float lb1[64], lb2[64], lw3[64];
    __shared__ _Float16 lh[4][16 * 72];

    const int tid = threadIdx.x;
    for (int i = tid; i < 128 * 64; i += 256) {
        int k = i >> 6, n = i & 63;
        int ks = k >> 5, q = (k >> 3) & 3, j = k & 7;
        int nt = n >> 4, s = n & 15;
        lw1x[(nt * 4 + ks) * 512 + (q * 16 + s) * 8 + j] = (_Float16)W1[i];
    }
    for (int i = tid; i < 64 * 64; i += 256) {
        int k = i >> 6, n = i & 63;
        int ks = k >> 5, q = (k >> 3) & 3, j = k & 7;
        int nt = n >> 4, s = n & 15;
        lw2x[(nt * 2 + ks) * 512 + (q * 16 + s) * 8 + j] = (_Float16)W2[i];
    }
    if (tid < 64) { lb1[tid] = b1[tid]; lb2[tid] = b2[tid]; lw3[tid] = W3[tid]; }
    __syncthreads();

    const int wave = tid >> 6;
    const int lane = tid & 63;
    const int s = lane & 15;
    const int q = lane >> 4;
    const float b3v = b3[0];
    const int T = nChunks * 64;
    const int stride = gridDim.x * 64;

    _Float16* myh = lh[wave];

    int t = blockIdx.x * 64 + wave * 16 + s;
    int kj = (t < T) ? idx_kj[t] : 0;

    for (int chunk = blockIdx.x; chunk < nChunks; chunk += gridDim.x) {
        const int t_next = t + stride;
        const int kj_next = idx_kj[(t_next < T) ? t_next : 0];

        const int ji = t >> 3;
        const int jn = kj >> 3;

        const float* mk = messages + (size_t)kj * MSGW + q * 8;
        const float* mj = messages + (size_t)ji * MSGW + q * 8;
        half8 afr[4];
        afr[0] = cvt8(mk);
        afr[1] = cvt8(mk + 32);
        afr[2] = cvt8(mj);
        afr[3] = cvt8(mj + 32);

        const float rk0 = r2[(size_t)kj * 2];
        const float rk1 = r2[(size_t)kj * 2 + 1];

        floatx4 acc[4];
#pragma unroll
        for (int nt = 0; nt < 4; ++nt) {
            float bv = lb1[nt * 16 + s];
            floatx4 iv = {bv, bv, bv, bv};
            acc[nt] = iv;
        }
#pragma unroll
        for (int ks = 0; ks < 4; ++ks)
#pragma unroll
            for (int nt = 0; nt < 4; ++nt) {
                half8 bf = *(const half8*)&lw1x[(nt * 4 + ks) * 512 + lane * 8];
                acc[nt] = __builtin_amdgcn_mfma_f32_16x16x32_f16(afr[ks], bf, acc[nt], 0, 0, 0);
            }

#pragma unroll
        for (int nt = 0; nt < 4; ++nt)
#pragma unroll
            for (int rr = 0; rr < 4; ++rr)
                myh[(q * 4 + rr) * 72 + nt * 16 + s] = (_Float16)softplus_f(acc[nt][rr]);
        __asm__ volatile("s_waitcnt lgkmcnt(0)" ::: "memory");

        half8 a2[2];
        a2[0] = *(const half8*)&myh[s * 72 + q * 8];
        a2[1] = *(const half8*)&myh[s * 72 + 32 + q * 8];
        __asm__ volatile("" ::: "memory");

        floatx4 acc2[4];
#pragma unroll
        for (int nt = 0; nt < 4; ++nt) {
            float bv = lb2[nt * 16 + s];
            floatx4 iv = {bv, bv, bv, bv};
            acc2[nt] = iv;
        }
#pragma unroll
        for (int ks = 0; ks < 2; ++ks)
#pragma unroll
            for (int nt = 0; nt < 4; ++nt) {
                half8 bf = *(const half8*)&lw2x[(nt * 2 + ks) * 512 + lane * 8];
                acc2[nt] = __builtin_amdgcn_mfma_f32_16x16x32_f16(a2[ks], bf, acc2[nt], 0, 0, 0);
            }

        float part[4];
#pragma unroll
        for (int rr = 0; rr < 4; ++rr) {
            float p = 0.0f;
#pragma unroll
            for (int nt = 0; nt < 4; ++nt)
                p += softplus_f(acc2[nt][rr]) * lw3[nt * 16 + s];
            part[rr] = p;
        }
#pragma unroll
        for (int mask = 1; mask < 16; mask <<= 1)
#pragma unroll
            for (int rr = 0; rr < 4; ++rr)
                part[rr] += __shfl_xor(part[rr], mask, 16);

        const int srcl = (s >> 2) << 4;
        float mr[4];
#pragma unroll
        for (int rr = 0; rr < 4; ++rr)
            mr[rr] = __shfl(part[rr], srcl, 64);
        const int rsel = s & 3;
        float m_mine = mr[0];
        m_mine = (rsel == 1) ? mr[1] : m_mine;
        m_mine = (rsel == 2) ? mr[2] : m_mine;
        m_mine = (rsel == 3) ? mr[3] : m_mine;
        m_mine += b3v;

        float c = m_mine * ((q & 1) ? rk1 : rk0);
        c += __shfl_xor(c, 1, 16);
        c += __shfl_xor(c, 2, 16);
        c += __shfl_xor(c, 4, 16);

        if ((s & 7) == 0) {
            const int aa = q >> 1, bb = q & 1;
            const float rj = r2[(size_t)ji * 2 + aa];
            atomicAdd(&sacc[(size_t)jn * 4 + aa * 2 + bb], rj * c);
            if (q == 0) atomicAdd(&cnt[jn], 8.0f);
        }

        t = t_next;
        kj = kj_next;
    }
}

__global__ void finalize_kernel(const float* __restrict__ sacc, const float* __restrict__ cnt,
                                float* __restrict__ out, int n4) {
    int i = blockIdx.x * 256 + threadIdx.x;
    if (i < n4) {
        float c = cnt[i >> 2];
        out[i] = sacc[i] / fmaxf(c, 1.0f);
    }
}

extern "C" void kernel_launch(void* const* d_in, const int* in_sizes, int n_in,
                              void* d_out, int out_size, void* d_ws, size_t ws_size,
                              hipStream_t stream) {
    const float* messages = (const float*)d_in[0];
    const float* r2       = (const float*)d_in[1];
    const float* W1       = (const float*)d_in[2];
    const float* b1       = (const float*)d_in[3];
    const float* W2       = (const float*)d_in[4];
    const float* b2       = (const float*)d_in[5];
    const float* W3       = (const float*)d_in[6];
    const float* b3       = (const float*)d_in[7];
    const int* idx_kj     = (const int*)d_in[8];

    const int T = in_sizes[8];          // 1,280,000 triplets
    const int E = T / DEG;              // 160,000 edges
    const int N = out_size / 4;         // 20,000 nodes
    float* sacc = (float*)d_ws;         // [N*4] pooled sums
    float* cntp = sacc + (size_t)N * 4; // [N] counts

    (void)hipMemsetAsync(d_ws, 0, (size_t)N * 5 * sizeof(float), stream);

    const int nChunks = T / 64;
    int grid = nChunks < 4096 ? nChunks : 4096;

    const size_t pqOff  = (((size_t)N * 5 * sizeof(float)) + 255) & ~(size_t)255;
    const size_t w1fOff = pqOff + (size_t)E * 128 * sizeof(_Float16);
    const size_t w2fOff = w1fOff + (size_t)16 * 512 * sizeof(_Float16);
    const size_t needWs = w2fOff + (size_t)8 * 512 * sizeof(_Float16);

    if (ws_size >= needWs) {
        _Float16* PQ  = (_Float16*)((char*)d_ws + pqOff);
        _Float16* W1f = (_Float16*)((char*)d_ws + w1fOff);
        _Float16* W2f = (_Float16*)((char*)d_ws + w2fOff);

        prep_weights_kernel<<<1, 256, 0, stream>>>(W1, W2, W1f, W2f);

        const int tiles = (E + 15) / 16;            // 16-edge wave tiles
        const int nbt = (tiles + 3) / 4;            // 4-wave block tiles
        const int epgrid = nbt < 640 ? nbt : 640;
        edge_proj_kernel<<<epgrid, 256, 0, stream>>>(messages, W1f, b1, PQ, E, nbt);

        triplet_mlp2_kernel<<<grid, 256, 0, stream>>>(PQ, r2, W2f, b2, W3, b3,
                                                      idx_kj, sacc, cntp, nChunks);
    } else {
        triplet_mlp_fb_kernel<<<grid, 256, 0, stream>>>(messages, r2, W1, b1, W2, b2, W3, b3,
                                                        idx_kj, sacc, cntp, nChunks);
    }

    const int n4 = N * 4;
    finalize_kernel<<<(n4 + 255) / 256, 256, 0, stream>>>(sacc, cntp, (float*)d_out, n4);
}

// Round 3
// 173.766 us; speedup vs baseline: 1.2555x; 1.0751x over previous
//
#include <hip/hip_runtime.h>

// MFMA fragment types (gfx950): 16x16x32 f16 -> A/B = 8 x _Float16, C/D = 4 x float
typedef _Float16 half8 __attribute__((ext_vector_type(8)));
typedef __fp16 fp16x2 __attribute__((ext_vector_type(2)));   // cvt_pkrtz return type
typedef float floatx4 __attribute__((ext_vector_type(4)));

#define MSGW 64      // message width
#define DEG 8        // fixed in-degree; triplets per edge

// softplus(x) = max(x,0) + ln(1 + exp(-|x|)), via native v_exp_f32/v_log_f32 (log2-based)
__device__ __forceinline__ float softplus_f(float x) {
    float ax = __builtin_fabsf(x);
    float t  = __builtin_amdgcn_exp2f(-1.44269504089f * ax);   // exp(-|x|)
    float l  = 0.69314718056f * __builtin_amdgcn_logf(1.0f + t);
    return fmaxf(x, 0.0f) + l;
}

__device__ __forceinline__ half8 cvt8(const float* p) {
    float4 x = *(const float4*)p;
    float4 y = *(const float4*)(p + 4);
    fp16x2 p0 = __builtin_amdgcn_cvt_pkrtz(x.x, x.y);
    fp16x2 p1 = __builtin_amdgcn_cvt_pkrtz(x.z, x.w);
    fp16x2 p2 = __builtin_amdgcn_cvt_pkrtz(y.x, y.y);
    fp16x2 p3 = __builtin_amdgcn_cvt_pkrtz(y.z, y.w);
    half8 h;
    h[0] = (_Float16)p0[0]; h[1] = (_Float16)p0[1];
    h[2] = (_Float16)p1[0]; h[3] = (_Float16)p1[1];
    h[4] = (_Float16)p2[0]; h[5] = (_Float16)p2[1];
    h[6] = (_Float16)p3[0]; h[7] = (_Float16)p3[1];
    return h;
}

// softplus over a half8 (fp16 in, fp16 out via cvt_pkrtz pairs)
__device__ __forceinline__ half8 sp8(half8 z) {
    half8 h;
#pragma unroll
    for (int j = 0; j < 8; j += 2) {
        fp16x2 pk = __builtin_amdgcn_cvt_pkrtz(softplus_f((float)z[j]),
                                               softplus_f((float)z[j + 1]));
        h[j] = (_Float16)pk[0]; h[j + 1] = (_Float16)pk[1];
    }
    return h;
}

// DPP-based cross-lane adds (register-only, no DS pipe).
// quad_perm xor1 = [1,0,3,2] = 0xB1 ; xor2 = [2,3,0,1] = 0x4E
// ROW_HALF_MIRROR = 0x141 (i <-> 7-i within each 8) ; ROW_MIRROR = 0x140 (i <-> 15-i)
template<int CTRL>
__device__ __forceinline__ float dpp_addf(float x) {
    int y = __builtin_amdgcn_update_dpp(0, __float_as_int(x), CTRL, 0xF, 0xF, true);
    return x + __int_as_float(y);
}
// full sum over the 16 lanes of a DPP row (mirror-based: direction-unambiguous)
__device__ __forceinline__ float red16(float x) {
    x = dpp_addf<0xB1>(x);   // + xor1  -> pair sums
    x = dpp_addf<0x4E>(x);   // + xor2  -> quad sums
    x = dpp_addf<0x141>(x);  // + half-mirror -> 8-lane sums
    x = dpp_addf<0x140>(x);  // + mirror      -> 16-lane sum (all lanes)
    return x;
}
// sum over each 8-lane half of a DPP row (lanes 0..7 get sum(0..7), 8..15 get sum(8..15))
__device__ __forceinline__ float red8(float x) {
    x = dpp_addf<0xB1>(x);
    x = dpp_addf<0x4E>(x);
    x = dpp_addf<0x141>(x);
    return x;
}

// ---------------------------------------------------------------------------
// Kernel 0: fused one-time prep (multi-block, grid-strided):
//   - zero the sacc/cnt accumulators (float4 stores)
//   - permute W1 -> W1f, W2 -> W2f into MFMA B-fragment lane order (fp16)
// frag layout: W*f[f*512 + lane*8 + j] = W[k = ks*32 + (lane>>4)*8 + j][n = nt*16 + (lane&15)]
//   (f = nt*2 + ks; W1f has nt 0..7 over [P|Q] 128 outputs, W2f nt 0..3)
// ---------------------------------------------------------------------------
__global__ void prep_kernel(const float* __restrict__ W1, const float* __restrict__ W2,
                            _Float16* __restrict__ W1f, _Float16* __restrict__ W2f,
                            float4* __restrict__ zs, int nz4) {
    const int g = blockIdx.x * 256 + threadIdx.x;
    const int stride = gridDim.x * 256;
    float4 z = {0.f, 0.f, 0.f, 0.f};
    for (int i = g; i < nz4; i += stride) zs[i] = z;
    for (int idx = g; idx < 16 * 512; idx += stride) {
        int f = idx >> 9, lane = (idx >> 3) & 63, j = idx & 7;
        int nt = f >> 1, ks = f & 1;
        int k = ks * 32 + (lane >> 4) * 8 + j;
        int np = nt * 16 + (lane & 15);
        float v = (np < 64) ? W1[k * 64 + np] : W1[(64 + k) * 64 + (np - 64)];
        W1f[idx] = (_Float16)v;
    }
    for (int idx = g; idx < 8 * 512; idx += stride) {
        int f = idx >> 9, lane = (idx >> 3) & 63, j = idx & 7;
        int nt = f >> 1, ks = f & 1;
        int k = ks * 32 + (lane >> 4) * 8 + j;
        int n = nt * 16 + (lane & 15);
        W2f[idx] = (_Float16)W2[k * 64 + n];
    }
}

// ---------------------------------------------------------------------------
// Kernel 1: per-edge layer-1 projection.
//   PQ[e][0:64]   = messages[e] @ W1[0:64, :]            (P, consumed via kj)
//   PQ[e][64:128] = messages[e] @ W1[64:128, :] + b1     (Q, consumed via ji)
// Stored fp16, [E x 128]. One wave = 16 edge rows, 16 MFMAs. ONE tile per wave,
// grid = ceil(E/64) blocks (max parallelism; memory-bound kernel).
// W1 staged by LINEAR half8 copy from pre-permuted W1f (16 KB, L2-hot).
// ---------------------------------------------------------------------------
__global__ __launch_bounds__(256, 2)
void edge_proj_kernel(const float* __restrict__ messages,
                      const _Float16* __restrict__ W1f, const float* __restrict__ b1,
                      _Float16* __restrict__ PQ, int E)
{
    __shared__ __align__(16) _Float16 lw1x[16 * 512];     // 16 B-fragments, lane-order
    __shared__ __align__(16) _Float16 lrep[4][16 * 132];  // per-wave C->row repack

    const int tid = threadIdx.x;
    for (int i = tid; i < 1024; i += 256)                 // 1024 x half8 = 16 KB linear copy
        *(half8*)&lw1x[i * 8] = *(const half8*)&W1f[i * 8];
    __syncthreads();

    const int wave = tid >> 6;
    const int lane = tid & 63;
    const int s = lane & 15;
    const int q = lane >> 4;
    const int e0 = (blockIdx.x * 4 + wave) * 16;
    if (e0 >= E) return;

    float b1v[4];
#pragma unroll
    for (int nt = 0; nt < 4; ++nt) b1v[nt] = b1[nt * 16 + s];

    int er = e0 + s; if (er >= E) er = E - 1;
    const float* mp = messages + (size_t)er * MSGW + q * 8;
    half8 af0 = cvt8(mp);
    half8 af1 = cvt8(mp + 32);

    floatx4 acc[8];
#pragma unroll
    for (int nt = 0; nt < 4; ++nt) { floatx4 z = {0.f, 0.f, 0.f, 0.f}; acc[nt] = z; }
#pragma unroll
    for (int nt = 4; nt < 8; ++nt) {
        float bv = b1v[nt - 4];
        floatx4 iv = {bv, bv, bv, bv};
        acc[nt] = iv;
    }
#pragma unroll
    for (int nt = 0; nt < 8; ++nt) {
        half8 bf0 = *(const half8*)&lw1x[(nt * 2 + 0) * 512 + lane * 8];
        acc[nt] = __builtin_amdgcn_mfma_f32_16x16x32_f16(af0, bf0, acc[nt], 0, 0, 0);
        half8 bf1 = *(const half8*)&lw1x[(nt * 2 + 1) * 512 + lane * 8];
        acc[nt] = __builtin_amdgcn_mfma_f32_16x16x32_f16(af1, bf1, acc[nt], 0, 0, 0);
    }

    // C-layout -> row-major fp16 via wave-private LDS, then coalesced 16B stores.
    _Float16* rep = lrep[wave];
#pragma unroll
    for (int nt = 0; nt < 8; ++nt)
#pragma unroll
        for (int rr = 0; rr < 4; ++rr)
            rep[(q * 4 + rr) * 132 + nt * 16 + s] = (_Float16)acc[nt][rr];
    __asm__ volatile("s_waitcnt lgkmcnt(0)" ::: "memory");

#pragma unroll
    for (int cc = 0; cc < 4; ++cc) {
        int c = cc * 64 + lane;
        int rrow = c >> 4, c16 = c & 15;
        half8 v = *(const half8*)&rep[rrow * 132 + c16 * 8];
        int eg = e0 + rrow;
        if (eg < E)
            *(half8*)&PQ[(size_t)eg * 128 + c16 * 8] = v;
    }
}

// ---------------------------------------------------------------------------
// Kernel 2: main triplet kernel. Zero LDS, no barriers. W2 fragments loaded
// from pre-permuted global W2f into 32 VGPRs. PQ/rk/rj gather software-
// pipelined one tile ahead (idx two ahead). Layer-3 reduce/distribute/pool all
// in DPP (register crossbar) + a single hoisted-address ds_bpermute.
// Structural facts: idx_ji[t]=t>>3, idx_j[t]=idx_kj[t]>>3.
// ---------------------------------------------------------------------------
__global__ __launch_bounds__(256, 3)
void triplet_mlp2_kernel(const _Float16* __restrict__ PQ,
                         const float* __restrict__ r2,
                         const _Float16* __restrict__ W2f,
                         const float* __restrict__ b2,
                         const float* __restrict__ W3, const float* __restrict__ b3,
                         const int* __restrict__ idx_kj,
                         float* __restrict__ sacc, float* __restrict__ cnt,
                         int nChunks)
{
    const int tid = threadIdx.x;
    const int wave = tid >> 6;
    const int lane = tid & 63;
    const int s = lane & 15;
    const int q = lane >> 4;

    // hoist weights: W2 fragments (32 VGPR), b2/W3 per-lane scalars, b3 uniform
    half8 w2f[2][4];
#pragma unroll
    for (int nt = 0; nt < 4; ++nt) {
        w2f[0][nt] = *(const half8*)&W2f[(nt * 2 + 0) * 512 + lane * 8];
        w2f[1][nt] = *(const half8*)&W2f[(nt * 2 + 1) * 512 + lane * 8];
    }
    float b2v[4], w3v[4];
#pragma unroll
    for (int nt = 0; nt < 4; ++nt) {
        b2v[nt] = b2[nt * 16 + s];
        w3v[nt] = W3[nt * 16 + s];
    }
    const float b3v = b3[0];
    const int aa = q >> 1;                       // dyad row component this lane handles
    // bpermute source lane for the m-distribute: lane (s,q) pulls from lane (s>>2)*16 + s,
    // which (after the local reg-select) holds msum[(s>>2)*4 + (s&3)] = msum[s].
    const int bperm_addr = (((s >> 2) << 4) + s) << 2;

    const int T = nChunks * 64;
    const int stride = gridDim.x * 64;

    // ---- pipeline prologue ----
    int t = blockIdx.x * 64 + wave * 16 + s;        // < T (grid <= nChunks)
    int kj = idx_kj[t];
    int t1 = t + stride; int t1c = (t1 < T) ? t1 : 0;
    int kjn = idx_kj[t1c];

    const _Float16* pk0 = PQ + (size_t)kj * 128 + q * 8;
    const _Float16* pj0 = PQ + (size_t)(t >> 3) * 128 + 64 + q * 8;
    half8 p0 = *(const half8*)pk0;
    half8 p1 = *(const half8*)(pk0 + 32);
    half8 q0 = *(const half8*)pj0;
    half8 q1 = *(const half8*)(pj0 + 32);
    float2 rkv = *(const float2*)(r2 + (size_t)kj * 2);
    float rjv = r2[(size_t)(t >> 3) * 2 + aa];

    for (int chunk = blockIdx.x; chunk < nChunks; chunk += gridDim.x) {
        // idx two tiles ahead; PQ/rk/rj one tile ahead (addresses ready: kjn from last iter)
        int t2 = t + 2 * stride; int t2c = (t2 < T) ? t2 : 0;
        const int kj2 = idx_kj[t2c];
        const _Float16* pkn = PQ + (size_t)kjn * 128 + q * 8;
        const _Float16* pjn = PQ + (size_t)(t1c >> 3) * 128 + 64 + q * 8;
        half8 np0 = *(const half8*)pkn;
        half8 np1 = *(const half8*)(pkn + 32);
        half8 nq0 = *(const half8*)pjn;
        half8 nq1 = *(const half8*)(pjn + 32);
        float2 nrk = *(const float2*)(r2 + (size_t)kjn * 2);
        float nrj = r2[(size_t)(t1c >> 3) * 2 + aa];

        const int ji = t >> 3;                   // idx_ji[t] structural
        const int jn = kj >> 3;                  // idx_j[t] structural
        (void)ji;

        // layer 1 = fp16 add of prefetched PQ fragments + softplus (A-frag layout)
        half8 z0 = p0 + q0;
        half8 z1 = p1 + q1;
        half8 a20 = sp8(z0);
        half8 a21 = sp8(z1);

        // ---- layer 2: [16 x 64] @ [64 x 64], B from registers ----
        floatx4 acc2[4];
#pragma unroll
        for (int nt = 0; nt < 4; ++nt) {
            float bv = b2v[nt];
            floatx4 iv = {bv, bv, bv, bv};
            acc2[nt] = iv;
        }
#pragma unroll
        for (int nt = 0; nt < 4; ++nt) {
            acc2[nt] = __builtin_amdgcn_mfma_f32_16x16x32_f16(a20, w2f[0][nt], acc2[nt], 0, 0, 0);
            acc2[nt] = __builtin_amdgcn_mfma_f32_16x16x32_f16(a21, w2f[1][nt], acc2[nt], 0, 0, 0);
        }

        // ---- layer 3: m = softplus(h2) . W3 ; reduce over 64 cols = 4 regs x 16 lanes ----
        float part[4];
#pragma unroll
        for (int rr = 0; rr < 4; ++rr) {
            float p = 0.0f;
#pragma unroll
            for (int nt = 0; nt < 4; ++nt)
                p += softplus_f(acc2[nt][rr]) * w3v[nt];
            part[rr] = red16(p);                 // all 16 row-lanes: msum[q*4+rr]
        }

        // distribute m to row-owner lanes: local reg-select then one bpermute
        const int rsel = s & 3;
        float mm = part[0];
        mm = (rsel == 1) ? part[1] : mm;
        mm = (rsel == 2) ? part[2] : mm;
        mm = (rsel == 3) ? part[3] : mm;         // lane (s,q) holds msum[q*4 + (s&3)]
        mm = __int_as_float(__builtin_amdgcn_ds_bpermute(bperm_addr, __float_as_int(mm)));
        mm += b3v;                               // lane (s,q) holds m for row s

        // per-edge pooled vector v[b] = sum_k m_k * rk_k[b]; quads carry b = q&1
        float c = mm * ((q & 1) ? rkv.y : rkv.x);
        c = red8(c);                             // lanes 0..7: edge A sum, 8..15: edge B

        if ((s & 7) == 0) {
            const int bb = q & 1;                       // dyad component: rj[aa]*v[bb]
            atomicAdd(&sacc[(size_t)jn * 4 + aa * 2 + bb], rjv * c);
            if (q == 0) atomicAdd(&cnt[jn], 8.0f);      // 8 triplets pooled per edge
        }

        // ---- rotate pipeline state ----
        t += stride;
        kj = kjn; kjn = kj2;
        t1c = t2c;
        p0 = np0; p1 = np1; q0 = nq0; q1 = nq1;
        rkv = nrk; rjv = nrj;
    }
}

// ---------------------------------------------------------------------------
// Fallback: verified single-pass kernel (used if ws_size can't hold PQ)
// ---------------------------------------------------------------------------
__global__ __launch_bounds__(256, 3)
void triplet_mlp_fb_kernel(const float* __restrict__ messages,
                           const float* __restrict__ r2,
                           const float* __restrict__ W1, const float* __restrict__ b1,
                           const float* __restrict__ W2, const float* __restrict__ b2,
                           const float* __restrict__ W3, const float* __restrict__ b3,
                           const int* __restrict__ idx_kj,
                           float* __restrict__ sacc, float* __restrict__ cnt,
                           int nChunks)
{
    __shared__ _Float16 lw1x[16 * 512];
    __shared__ _Float16 lw2x[8 * 512];
    __shared__ float lb1[64], lb2[64], lw3[64];
    __shared__ _Float16 lh[4][16 * 72];

    const int tid = threadIdx.x;
    for (int i = tid; i < 128 * 64; i += 256) {
        int k = i >> 6, n = i & 63;
        int ks = k >> 5, q = (k >> 3) & 3, j = k & 7;
        int nt = n >> 4, s = n & 15;
        lw1x[(nt * 4 + ks) * 512 + (q * 16 + s) * 8 + j] = (_Float16)W1[i];
    }
    for (int i = tid; i < 64 * 64; i += 256) {
        int k = i >> 6, n = i & 63;
        int ks = k >> 5, q = (k >> 3) & 3, j = k & 7;
        int nt = n >> 4, s = n & 15;
        lw2x[(nt * 2 + ks) * 512 + (q * 16 + s) * 8 + j] = (_Float16)W2[i];
    }
    if (tid < 64) { lb1[tid] = b1[tid]; lb2[tid] = b2[tid]; lw3[tid] = W3[tid]; }
    __syncthreads();

    const int wave = tid >> 6;
    const int lane = tid & 63;
    const int s = lane & 15;
    const int q = lane >> 4;
    const float b3v = b3[0];
    const int T = nChunks * 64;
    const int stride = gridDim.x * 64;

    _Float16* myh = lh[wave];

    int t = blockIdx.x * 64 + wave * 16 + s;
    int kj = (t < T) ? idx_kj[t] : 0;

    for (int chunk = blockIdx.x; chunk < nChunks; chunk += gridDim.x) {
        const int t_next = t + stride;
        const int kj_next = idx_kj[(t_next < T) ? t_next : 0];

        const int ji = t >> 3;
        const int jn = kj >> 3;

        const float* mk = messages + (size_t)kj * MSGW + q * 8;
        const float* mj = messages + (size_t)ji * MSGW + q * 8;
        half8 afr[4];
        afr[0] = cvt8(mk);
        afr[1] = cvt8(mk + 32);
        afr[2] = cvt8(mj);
        afr[3] = cvt8(mj + 32);

        const float rk0 = r2[(size_t)kj * 2];
        const float rk1 = r2[(size_t)kj * 2 + 1];

        floatx4 acc[4];
#pragma unroll
        for (int nt = 0; nt < 4; ++nt) {
            float bv = lb1[nt * 16 + s];
            floatx4 iv = {bv, bv, bv, bv};
            acc[nt] = iv;
        }
#pragma unroll
        for (int ks = 0; ks < 4; ++ks)
#pragma unroll
            for (int nt = 0; nt < 4; ++nt) {
                half8 bf = *(const half8*)&lw1x[(nt * 4 + ks) * 512 + lane * 8];
                acc[nt] = __builtin_amdgcn_mfma_f32_16x16x32_f16(afr[ks], bf, acc[nt], 0, 0, 0);
            }

#pragma unroll
        for (int nt = 0; nt < 4; ++nt)
#pragma unroll
            for (int rr = 0; rr < 4; ++rr)
                myh[(q * 4 + rr) * 72 + nt * 16 + s] = (_Float16)softplus_f(acc[nt][rr]);
        __asm__ volatile("s_waitcnt lgkmcnt(0)" ::: "memory");

        half8 a2[2];
        a2[0] = *(const half8*)&myh[s * 72 + q * 8];
        a2[1] = *(const half8*)&myh[s * 72 + 32 + q * 8];
        __asm__ volatile("" ::: "memory");

        floatx4 acc2[4];
#pragma unroll
        for (int nt = 0; nt < 4; ++nt) {
            float bv = lb2[nt * 16 + s];
            floatx4 iv = {bv, bv, bv, bv};
            acc2[nt] = iv;
        }
#pragma unroll
        for (int ks = 0; ks < 2; ++ks)
#pragma unroll
            for (int nt = 0; nt < 4; ++nt) {
                half8 bf = *(const half8*)&lw2x[(nt * 2 + ks) * 512 + lane * 8];
                acc2[nt] = __builtin_amdgcn_mfma_f32_16x16x32_f16(a2[ks], bf, acc2[nt], 0, 0, 0);
            }

        float part[4];
#pragma unroll
        for (int rr = 0; rr < 4; ++rr) {
            float p = 0.0f;
#pragma unroll
            for (int nt = 0; nt < 4; ++nt)
                p += softplus_f(acc2[nt][rr]) * lw3[nt * 16 + s];
            part[rr] = p;
        }
#pragma unroll
        for (int mask = 1; mask < 16; mask <<= 1)
#pragma unroll
            for (int rr = 0; rr < 4; ++rr)
                part[rr] += __shfl_xor(part[rr], mask, 16);

        const int srcl = (s >> 2) << 4;
        float mr[4];
#pragma unroll
        for (int rr = 0; rr < 4; ++rr)
            mr[rr] = __shfl(part[rr], srcl, 64);
        const int rsel = s & 3;
        float m_mine = mr[0];
        m_mine = (rsel == 1) ? mr[1] : m_mine;
        m_mine = (rsel == 2) ? mr[2] : m_mine;
        m_mine = (rsel == 3) ? mr[3] : m_mine;
        m_mine += b3v;

        float c = m_mine * ((q & 1) ? rk1 : rk0);
        c += __shfl_xor(c, 1, 16);
        c += __shfl_xor(c, 2, 16);
        c += __shfl_xor(c, 4, 16);

        if ((s & 7) == 0) {
            const int aa = q >> 1, bb = q & 1;
            const float rj = r2[(size_t)ji * 2 + aa];
            atomicAdd(&sacc[(size_t)jn * 4 + aa * 2 + bb], rj * c);
            if (q == 0) atomicAdd(&cnt[jn], 8.0f);
        }

        t = t_next;
        kj = kj_next;
    }
}

__global__ void finalize_kernel(const float* __restrict__ sacc, const float* __restrict__ cnt,
                                float* __restrict__ out, int n4) {
    int i = blockIdx.x * 256 + threadIdx.x;
    if (i < n4) {
        float c = cnt[i >> 2];
        out[i] = sacc[i] / fmaxf(c, 1.0f);
    }
}

extern "C" void kernel_launch(void* const* d_in, const int* in_sizes, int n_in,
                              void* d_out, int out_size, void* d_ws, size_t ws_size,
                              hipStream_t stream) {
    const float* messages = (const float*)d_in[0];
    const float* r2       = (const float*)d_in[1];
    const float* W1       = (const float*)d_in[2];
    const float* b1       = (const float*)d_in[3];
    const float* W2       = (const float*)d_in[4];
    const float* b2       = (const float*)d_in[5];
    const float* W3       = (const float*)d_in[6];
    const float* b3       = (const float*)d_in[7];
    const int* idx_kj     = (const int*)d_in[8];

    const int T = in_sizes[8];          // 1,280,000 triplets
    const int E = T / DEG;              // 160,000 edges
    const int N = out_size / 4;         // 20,000 nodes
    float* sacc = (float*)d_ws;         // [N*4] pooled sums
    float* cntp = sacc + (size_t)N * 4; // [N] counts

    const int nChunks = T / 64;
    int grid = nChunks < 4096 ? nChunks : 4096;

    const size_t pqOff  = (((size_t)N * 5 * sizeof(float)) + 255) & ~(size_t)255;
    const size_t w1fOff = pqOff + (size_t)E * 128 * sizeof(_Float16);
    const size_t w2fOff = w1fOff + (size_t)16 * 512 * sizeof(_Float16);
    const size_t needWs = w2fOff + (size_t)8 * 512 * sizeof(_Float16);

    if (ws_size >= needWs) {
        _Float16* PQ  = (_Float16*)((char*)d_ws + pqOff);
        _Float16* W1f = (_Float16*)((char*)d_ws + w1fOff);
        _Float16* W2f = (_Float16*)((char*)d_ws + w2fOff);

        // fused zero + weight permute (replaces memset + single-block prep)
        prep_kernel<<<48, 256, 0, stream>>>(W1, W2, W1f, W2f,
                                            (float4*)d_ws, (N * 5) / 4);

        const int tiles = (E + 15) / 16;            // 16-edge wave tiles
        const int epgrid = (tiles + 3) / 4;         // one tile per wave, 4 waves/block
        edge_proj_kernel<<<epgrid, 256, 0, stream>>>(messages, W1f, b1, PQ, E);

        triplet_mlp2_kernel<<<grid, 256, 0, stream>>>(PQ, r2, W2f, b2, W3, b3,
                                                      idx_kj, sacc, cntp, nChunks);
    } else {
        (void)hipMemsetAsync(d_ws, 0, (size_t)N * 5 * sizeof(float), stream);
        triplet_mlp_fb_kernel<<<grid, 256, 0, stream>>>(messages, r2, W1, b1, W2, b2, W3, b3,
                                                        idx_kj, sacc, cntp, nChunks);
    }

    const int n4 = N * 4;
    finalize_kernel<<<(n4 + 255) / 256, 256, 0, stream>>>(sacc, cntp, (float*)d_out, n4);
}